// Round 1
// 438.230 us; speedup vs baseline: 1.0147x; 1.0147x over previous
//
#include <hip/hip_runtime.h>
#include <math.h>

#define T_TOKENS 2048
#define DMODEL   1024
#define HID      4096
#define NEXP     8
#define MAX_TILES 32

typedef float  f32x4  __attribute__((ext_vector_type(4)));
typedef short  bf16x8 __attribute__((ext_vector_type(8)));

__device__ __forceinline__ unsigned short f2bf(float f) {
    union { float f; unsigned u; } v; v.f = f;
    unsigned u = v.u;
    unsigned r = (u + 0x7FFFu + ((u >> 16) & 1u)) >> 16;   // RNE
    return (unsigned short)r;
}

// packed f32x2 -> bf16x2 (RNE), lo -> low 16 bits
__device__ __forceinline__ unsigned pk2bf(float lo, float hi) {
    unsigned r;
    asm("v_cvt_pk_bf16_f32 %0, %1, %2" : "=v"(r) : "v"(lo), "v"(hi));
    return r;
}

__device__ __forceinline__ float f4get(const float4& v, int i) {
    return i == 0 ? v.x : i == 1 ? v.y : i == 2 ? v.z : v.w;
}

__device__ __forceinline__ void async_copy16(const void* g, void* l) {
    __builtin_amdgcn_global_load_lds(
        (const __attribute__((address_space(1))) void*)g,
        (__attribute__((address_space(3))) void*)l,
        16, 0, 0);
}

// ---------------- router: logits -> top2 weight; also x f32 -> bf16 --------
__global__ __launch_bounds__(64) void router_kernel(
    const float* __restrict__ x, const float* __restrict__ Wr,
    int* counts, int* expert_of, int* slot_of, float* wt_of,
    unsigned short* __restrict__ Xbf) {
    int t = blockIdx.x;
    int lane = threadIdx.x;
    const float* xr = x + (size_t)t * DMODEL;
    unsigned short* xb = Xbf + (size_t)t * DMODEL;
    float p[NEXP];
#pragma unroll
    for (int e = 0; e < NEXP; ++e) p[e] = 0.f;
#pragma unroll
    for (int q = 0; q < 4; ++q) {
        int d = q * 256 + lane * 4;
        float4 v = *(const float4*)(xr + d);
        ushort4 b;
        b.x = f2bf(v.x); b.y = f2bf(v.y); b.z = f2bf(v.z); b.w = f2bf(v.w);
        *(ushort4*)(xb + d) = b;
#pragma unroll
        for (int j = 0; j < 4; ++j) {
            float xv = f4get(v, j);
            const float* wr = Wr + (size_t)(d + j) * NEXP;
#pragma unroll
            for (int e = 0; e < NEXP; ++e) p[e] += xv * wr[e];
        }
    }
#pragma unroll
    for (int e = 0; e < NEXP; ++e) {
        for (int off = 32; off > 0; off >>= 1)
            p[e] += __shfl_down(p[e], off, 64);
    }
    if (lane == 0) {
        int i0 = 0; float v0 = p[0];
        for (int e = 1; e < NEXP; ++e) if (p[e] > v0) { v0 = p[e]; i0 = e; }
        float v1 = -INFINITY;
        for (int e = 0; e < NEXP; ++e) if (e != i0 && p[e] > v1) v1 = p[e];
        float w = 1.f / (1.f + expf(v1 - v0));
        expert_of[t] = i0;
        wt_of[t] = w;
        slot_of[t] = atomicAdd(&counts[i0], 1);
    }
}

// ---------------- scan + tile list + scatter (one small block) -------------
__global__ void scan_scatter_kernel(const int* counts, int* offsets,
                                    int* tileE, int* tileM, int* tileCount,
                                    const int* expert_of, const int* slot_of,
                                    int* perm) {
    __shared__ int soff[NEXP];
    if (threadIdx.x == 0) {
        int run = 0, tc = 0;
        for (int e = 0; e < NEXP; ++e) {
            offsets[e] = run; soff[e] = run;
            for (int m0 = 0; m0 < counts[e]; m0 += 128) {
                tileE[tc] = e; tileM[tc] = m0; ++tc;
            }
            run += counts[e];
        }
        *tileCount = tc;
    }
    __syncthreads();
    for (int t = threadIdx.x; t < T_TOKENS; t += blockDim.x)
        perm[soff[expert_of[t]] + slot_of[t]] = t;
}

// ===========================================================================
// GEMM1: H = GELU(Xbf[perm] @ W1) — W1 read as f32, converted+transposed into
// swizzled LDS in the staging path. 2-phase pipelined, 1 barrier per k-step.
// ===========================================================================
__global__ __launch_bounds__(256, 2) void gemm1_kernel(
    const unsigned short* __restrict__ Xbf, const float* __restrict__ W1,
    const int* __restrict__ counts, const int* __restrict__ offsets,
    const int* __restrict__ perm, const int* __restrict__ tileE,
    const int* __restrict__ tileM, const int* __restrict__ tileCount,
    unsigned short* __restrict__ H) {

    const int NT = HID / 128;                 // 32
    int tile = blockIdx.x / NT;
    int nt   = blockIdx.x % NT;
    if (tile >= *tileCount) return;
    int e = tileE[tile], m0 = tileM[tile];
    int rows_e = counts[e], base = offsets[e];
    int n0 = nt * 128;

    __shared__ unsigned short Alds[2][128 * 64];
    __shared__ unsigned short Blds[2][128 * 64];

    int tid  = threadIdx.x;
    int lane = tid & 63;
    int wid  = tid >> 6;
    int wm = wid >> 1, wn = wid & 1;
    const int swz = (lane & 7) << 4;          // fragment-read XOR swizzle

    // ---- A staging: global_load_lds, per-lane PRE-SWIZZLED global source ----
    const unsigned short* ag[4];
    int aoff[4];
#pragma unroll
    for (int p = 0; p < 4; ++p) {
        int idx = p * 256 + tid;
        int row = idx >> 3;
        int seg = (idx & 7) ^ (row & 7);      // inverse swizzle on source
        int r = m0 + row;
        int tok = perm[base + (r < rows_e ? r : rows_e - 1)];
        ag[p] = Xbf + (size_t)tok * DMODEL + seg * 8;
        aoff[p] = idx * 16;                   // linear LDS byte offset
    }

    // ---- B staging: thread owns k-quad (tid&15)*4, n-octet (tid>>4)*8 ----
    const int kq4 = (tid & 15) * 4;
    const int nb  = (tid >> 4) * 8;
    const float* bsrc = W1 + ((size_t)e * DMODEL + kq4) * HID + n0 + nb;
    float4 breg[8];                           // 4 k-rows x 2 float4

    f32x4 acc[4][4];
#pragma unroll
    for (int i = 0; i < 4; ++i)
#pragma unroll
        for (int j = 0; j < 4; ++j) acc[i][j] = (f32x4){0.f, 0.f, 0.f, 0.f};

#define G_ISSUE(kt, BUF, STRIDE) do {                                         \
    _Pragma("unroll")                                                         \
    for (int r_ = 0; r_ < 4; ++r_) {                                          \
        _Pragma("unroll")                                                     \
        for (int q_ = 0; q_ < 2; ++q_)                                        \
            breg[r_*2+q_] = *(const float4*)(bsrc + ((size_t)(kt)*64 + r_) * (STRIDE) + q_*4); \
    }                                                                         \
    _Pragma("unroll")                                                         \
    for (int p_ = 0; p_ < 4; ++p_)                                            \
        async_copy16(ag[p_] + (kt) * 64, (char*)Alds[BUF] + aoff[p_]);        \
} while (0)

#define G_WRITEB(BUF) do {                                                    \
    char* bb_ = (char*)Blds[BUF];                                             \
    _Pragma("unroll")                                                         \
    for (int j_ = 0; j_ < 8; ++j_) {                                          \
        unsigned lo_ = pk2bf(f4get(breg[0 + (j_>>2)], j_&3),                  \
                             f4get(breg[2 + (j_>>2)], j_&3));                 \
        unsigned hi_ = pk2bf(f4get(breg[4 + (j_>>2)], j_&3),                  \
                             f4get(breg[6 + (j_>>2)], j_&3));                 \
        unsigned long long w_ = ((unsigned long long)hi_ << 32) | lo_;        \
        *(unsigned long long*)(bb_ + (nb + j_) * 128 + ((kq4 * 2) ^ (j_ << 4))) = w_; \
    }                                                                         \
} while (0)

#define G_COMPUTE(BUF) do {                                                   \
    const char* ab_ = (const char*)Alds[BUF];                                 \
    const char* bb_ = (const char*)Blds[BUF];                                 \
    _Pragma("unroll")                                                         \
    for (int ks_ = 0; ks_ < 2; ++ks_) {                                       \
        int kb_ = (ks_ * 32 + ((lane >> 4) * 8)) * 2;                         \
        bf16x8 af_[4], bf_[4];                                                \
        _Pragma("unroll")                                                     \
        for (int i_ = 0; i_ < 4; ++i_) {                                      \
            int m_ = wm * 64 + i_ * 16 + (lane & 15);                         \
            af_[i_] = *(const bf16x8*)(ab_ + m_ * 128 + (kb_ ^ swz));         \
            int n_ = wn * 64 + i_ * 16 + (lane & 15);                         \
            bf_[i_] = *(const bf16x8*)(bb_ + n_ * 128 + (kb_ ^ swz));         \
        }                                                                     \
        _Pragma("unroll")                                                     \
        for (int i_ = 0; i_ < 4; ++i_)                                        \
            _Pragma("unroll")                                                 \
            for (int j_ = 0; j_ < 4; ++j_)                                    \
                acc[i_][j_] = __builtin_amdgcn_mfma_f32_16x16x32_bf16(af_[i_], bf_[j_], acc[i_][j_], 0, 0, 0); \
    }                                                                         \
} while (0)

    // prologue: stage k-tile 0 into buf0
    G_ISSUE(0, 0, HID);
    G_WRITEB(0);
    __syncthreads();

#pragma unroll 1
    for (int t = 0; t < 16; t += 2) {
        G_ISSUE(t + 1, 1, HID);               // prefetch t+1 into buf1
        G_COMPUTE(0);
        G_WRITEB(1);
        __syncthreads();
        if (t + 2 < 16) G_ISSUE(t + 2, 0, HID);
        G_COMPUTE(1);
        if (t + 2 < 16) G_WRITEB(0);
        __syncthreads();
    }

    int quad = lane >> 4, col = lane & 15;
#pragma unroll
    for (int i = 0; i < 4; ++i)
#pragma unroll
        for (int j = 0; j < 4; ++j)
#pragma unroll
            for (int r = 0; r < 4; ++r) {
                int ml = wm * 64 + i * 16 + quad * 4 + r;
                if (m0 + ml < rows_e) {
                    int n = n0 + wn * 64 + j * 16 + col;
                    float v = acc[i][j][r];
                    float g = 0.5f * v * (1.0f + erff(v * 0.70710678118654752f));
                    H[(size_t)(base + m0 + ml) * HID + n] = f2bf(g);
                }
            }
}

// ===========================================================================
// GEMM2 (split-K=4): out += wt * (H @ W2) — same fused structure.
// ===========================================================================
__global__ __launch_bounds__(256, 2) void gemm2_kernel(
    const unsigned short* __restrict__ H, const float* __restrict__ W2,
    const int* __restrict__ counts, const int* __restrict__ offsets,
    const int* __restrict__ perm, const float* __restrict__ wt_of,
    const int* __restrict__ tileE, const int* __restrict__ tileM,
    const int* __restrict__ tileCount, float* __restrict__ out) {

    const int NT = DMODEL / 128;              // 8
    const int SK = 4;
    int tile = blockIdx.x / (NT * SK);
    int rem  = blockIdx.x % (NT * SK);
    int nt   = rem >> 2;
    int sk   = rem & 3;
    if (tile >= *tileCount) return;
    int e = tileE[tile], m0 = tileM[tile];
    int rows_e = counts[e], base = offsets[e];
    int n0 = nt * 128;
    int kbeg = sk * (HID / SK);               // 1024-wide K slice

    __shared__ unsigned short Alds[2][128 * 64];
    __shared__ unsigned short Blds[2][128 * 64];
    __shared__ int   rowTok[128];
    __shared__ float rowW[128];

    int tid  = threadIdx.x;
    int lane = tid & 63;
    int wid  = tid >> 6;
    int wm = wid >> 1, wn = wid & 1;
    const int swz = (lane & 7) << 4;

    if (tid < 128) {
        int r = m0 + tid;
        if (r < rows_e) {
            int tok = perm[base + r];
            rowTok[tid] = tok;
            rowW[tid]   = wt_of[tok];
        } else { rowTok[tid] = 0; rowW[tid] = 0.f; }
    }

    const unsigned short* ag[4];
    int aoff[4];
#pragma unroll
    for (int p = 0; p < 4; ++p) {
        int idx = p * 256 + tid;
        int row = idx >> 3;
        int seg = (idx & 7) ^ (row & 7);
        int hr = base + m0 + row;
        if (hr > T_TOKENS - 1) hr = T_TOKENS - 1;
        ag[p] = H + (size_t)hr * HID + kbeg + seg * 8;
        aoff[p] = idx * 16;
    }

    const int kq4 = (tid & 15) * 4;
    const int nb  = (tid >> 4) * 8;
    const float* bsrc = W2 + ((size_t)e * HID + kbeg + kq4) * DMODEL + n0 + nb;
    float4 breg[8];

    f32x4 acc[4][4];
#pragma unroll
    for (int i = 0; i < 4; ++i)
#pragma unroll
        for (int j = 0; j < 4; ++j) acc[i][j] = (f32x4){0.f, 0.f, 0.f, 0.f};

    G_ISSUE(0, 0, DMODEL);
    G_WRITEB(0);
    __syncthreads();

#pragma unroll 1
    for (int t = 0; t < 16; t += 2) {
        G_ISSUE(t + 1, 1, DMODEL);
        G_COMPUTE(0);
        G_WRITEB(1);
        __syncthreads();
        if (t + 2 < 16) G_ISSUE(t + 2, 0, DMODEL);
        G_COMPUTE(1);
        if (t + 2 < 16) G_WRITEB(0);
        __syncthreads();
    }

    int quad = lane >> 4, col = lane & 15;
#pragma unroll
    for (int i = 0; i < 4; ++i)
#pragma unroll
        for (int j = 0; j < 4; ++j)
#pragma unroll
            for (int r = 0; r < 4; ++r) {
                int ml = wm * 64 + i * 16 + quad * 4 + r;
                if (m0 + ml < rows_e) {
                    int tok = rowTok[ml];
                    float w = rowW[ml];
                    int n = n0 + wn * 64 + j * 16 + col;
                    atomicAdd(&out[(size_t)tok * DMODEL + n], w * acc[i][j][r]);
                }
            }
}

extern "C" void kernel_launch(void* const* d_in, const int* in_sizes, int n_in,
                              void* d_out, int out_size, void* d_ws, size_t ws_size,
                              hipStream_t stream) {
    const float* x  = (const float*)d_in[0];
    const float* Wr = (const float*)d_in[1];
    const float* W1 = (const float*)d_in[2];
    const float* W2 = (const float*)d_in[3];
    float* out = (float*)d_out;

    char* ws = (char*)d_ws;
    int*   counts    = (int*)(ws);
    int*   offsets   = (int*)(ws + 64);
    int*   tileCount = (int*)(ws + 128);
    int*   tileE     = (int*)(ws + 256);
    int*   tileM     = (int*)(ws + 256 + 4 * MAX_TILES);
    int*   expert_of = (int*)(ws + 1024);
    int*   slot_of   = (int*)(ws + 1024 + 8192);
    float* wt_of     = (float*)(ws + 1024 + 16384);
    int*   perm      = (int*)(ws + 1024 + 24576);
    size_t off = 65536;
    unsigned short* Xbf  = (unsigned short*)(ws + off); off += (size_t)T_TOKENS * DMODEL * 2;  // 4 MB
    unsigned short* Hbuf = (unsigned short*)(ws + off);                                        // 16 MB

    hipMemsetAsync(counts, 0, 64, stream);
    hipMemsetAsync(out, 0, (size_t)T_TOKENS * DMODEL * sizeof(float), stream);

    router_kernel<<<T_TOKENS, 64, 0, stream>>>(x, Wr, counts, expert_of, slot_of, wt_of, Xbf);
    scan_scatter_kernel<<<1, 256, 0, stream>>>(counts, offsets, tileE, tileM, tileCount,
                                               expert_of, slot_of, perm);

    gemm1_kernel<<<MAX_TILES * (HID / 128), 256, 0, stream>>>(
        Xbf, W1, counts, offsets, perm, tileE, tileM, tileCount, Hbuf);
    gemm2_kernel<<<MAX_TILES * (DMODEL / 128) * 4, 256, 0, stream>>>(
        Hbuf, W2, counts, offsets, perm, wt_of, tileE, tileM, tileCount, out);
}